// Round 1
// baseline (1012.368 us; speedup 1.0000x reference)
//
#include <hip/hip_runtime.h>

// ---------------- CSR build ----------------

__global__ void zero_int_kernel(int* __restrict__ p, int n) {
    int i = blockIdx.x * blockDim.x + threadIdx.x;
    if (i < n) p[i] = 0;
}

__global__ void hist_kernel(const int* __restrict__ dst, int n, int* __restrict__ deg) {
    int i = blockIdx.x * blockDim.x + threadIdx.x;
    if (i < n) atomicAdd(&deg[dst[i]], 1);
}

// single-workgroup exclusive scan over n (<= ~64k) entries
__global__ __launch_bounds__(1024) void scan_kernel(const int* __restrict__ deg,
                                                    int* __restrict__ rs, int n) {
    __shared__ int sums[1024];
    int t = threadIdx.x;
    int chunk = (n + 1023) >> 10;
    int lo = min(t * chunk, n);
    int hi = min(lo + chunk, n);
    int s = 0;
    for (int i = lo; i < hi; ++i) s += deg[i];
    sums[t] = s;
    __syncthreads();
    if (t == 0) {
        int run = 0;
        for (int i = 0; i < 1024; ++i) { int v = sums[i]; sums[i] = run; run += v; }
        rs[n] = run;
    }
    __syncthreads();
    int run = sums[t];
    for (int i = lo; i < hi; ++i) { rs[i] = run; run += deg[i]; }
}

__global__ void scatter_kernel(const int* __restrict__ src, const int* __restrict__ dst, int n,
                               const int* __restrict__ rs, int* __restrict__ cur,
                               int* __restrict__ esrc) {
    int i = blockIdx.x * blockDim.x + threadIdx.x;
    if (i < n) {
        int d = dst[i];
        int p = atomicAdd(&cur[d], 1);
        esrc[rs[d] + p] = src[i];
    }
}

// ---------------- GEMM: Y[N x M] = X[N x 128] @ W[128 x M], fp32 ----------------

template<int M>
__global__ __launch_bounds__(256) void gemm_kernel(const float* __restrict__ X,
                                                   const float* __restrict__ W,
                                                   float* __restrict__ Y, int N) {
    constexpr int CG = M / 4;       // column groups of 4
    constexpr int RG = 256 / CG;    // row groups
    constexpr int RPT = 32 / RG;    // rows per thread (tile = 32 rows)
    __shared__ float xs[128 * 33];  // transposed tile xs[k*33 + r], +1 pad vs 32
    const int row0 = blockIdx.x * 32;
    const int t = threadIdx.x;
    #pragma unroll
    for (int i = 0; i < 16; ++i) {
        int f = t + i * 256;
        int r = f >> 7, k = f & 127;
        int grow = row0 + r;
        xs[k * 33 + r] = (grow < N) ? X[(size_t)grow * 128 + k] : 0.f;
    }
    __syncthreads();
    const int c0 = (t % CG) * 4;
    const int r0 = (t / CG) * RPT;
    float acc[RPT][4];
    #pragma unroll
    for (int j = 0; j < RPT; ++j)
        acc[j][0] = acc[j][1] = acc[j][2] = acc[j][3] = 0.f;
    #pragma unroll 4
    for (int k = 0; k < 128; ++k) {
        const float4 wv = *(const float4*)&W[k * M + c0];
        #pragma unroll
        for (int j = 0; j < RPT; ++j) {
            float xv = xs[k * 33 + r0 + j];
            acc[j][0] += xv * wv.x;
            acc[j][1] += xv * wv.y;
            acc[j][2] += xv * wv.z;
            acc[j][3] += xv * wv.w;
        }
    }
    #pragma unroll
    for (int j = 0; j < RPT; ++j) {
        int rr = row0 + r0 + j;
        if (rr < N) *(float4*)&Y[(size_t)rr * M + c0] = *(const float4*)acc[j];
    }
}

// ---------------- Aggregation: one wave per dst node ----------------
// out[dst] = (sum over in-edges of h[src]) / max(deg,1) + bias   (+= if ACCUM)

template<int D, bool ACCUM>
__global__ __launch_bounds__(256) void agg_kernel(const float* __restrict__ h,
                                                  const int* __restrict__ esrc,
                                                  const int* __restrict__ rs,
                                                  const float* __restrict__ bias,
                                                  float* __restrict__ out, int n) {
    int wid = (int)((blockIdx.x * 256u + threadIdx.x) >> 6);
    int lane = threadIdx.x & 63;
    if (wid >= n) return;
    int e0 = rs[wid], e1 = rs[wid + 1];
    constexpr int J = D / 64;
    float acc[J];
    #pragma unroll
    for (int j = 0; j < J; ++j) acc[j] = 0.f;
    for (int e = e0; e < e1; ++e) {
        const float* hp = h + (size_t)esrc[e] * D;
        #pragma unroll
        for (int j = 0; j < J; ++j) acc[j] += hp[lane + j * 64];
    }
    float inv = 1.f / (float)max(e1 - e0, 1);
    #pragma unroll
    for (int j = 0; j < J; ++j) {
        float v = acc[j] * inv + bias[lane + j * 64];
        size_t o = (size_t)wid * D + lane + j * 64;
        if (ACCUM) out[o] += v; else out[o] = v;
    }
}

// ---------------- launch ----------------

extern "C" void kernel_launch(void* const* d_in, const int* in_sizes, int n_in,
                              void* d_out, int out_size, void* d_ws, size_t ws_size,
                              hipStream_t stream) {
    const float* x_drug = (const float*)d_in[0];
    const float* x_prot = (const float*)d_in[1];
    const int* src[3] = { (const int*)d_in[2], (const int*)d_in[4], (const int*)d_in[6] };
    const int* dst[3] = { (const int*)d_in[3], (const int*)d_in[5], (const int*)d_in[7] };
    const float* W1[3] = { (const float*)d_in[8],  (const float*)d_in[10], (const float*)d_in[12] };
    const float* b1[3] = { (const float*)d_in[9],  (const float*)d_in[11], (const float*)d_in[13] };
    const float* W2[3] = { (const float*)d_in[14], (const float*)d_in[16], (const float*)d_in[18] };
    const float* b2[3] = { (const float*)d_in[15], (const float*)d_in[17], (const float*)d_in[19] };

    const int ND = in_sizes[0] / 128;
    const int NP = in_sizes[1] / 128;
    const int EC[3] = { in_sizes[2], in_sizes[4], in_sizes[6] };
    const int ndst[3] = { ND, NP, NP };
    float* out = (float*)d_out;

    // workspace layout
    char* w = (char*)d_ws;
    const size_t maxN = (size_t)(ND > NP ? ND : NP);
    float* tbuf = (float*)w; w += maxN * 128 * sizeof(float);       // 25.6 MB
    float* h_d  = (float*)w; w += (size_t)ND * 128 * sizeof(float); // 25.6 MB
    float* h_p  = (float*)w; w += (size_t)NP * 128 * sizeof(float); // 25.6 MB
    int* ibase = (int*)w;
    int* deg[3]; int* cur[3]; int* rs[3]; int* esrc[3];
    int* ip = ibase;
    for (int r = 0; r < 3; ++r) { deg[r] = ip; ip += ndst[r]; }
    for (int r = 0; r < 3; ++r) { cur[r] = ip; ip += ndst[r]; }
    const int nzero = (int)(ip - ibase);          // deg+cur zeroed in one launch
    for (int r = 0; r < 3; ++r) { rs[r] = ip; ip += ndst[r] + 1; }
    for (int r = 0; r < 3; ++r) { esrc[r] = ip; ip += EC[r]; }

    // ---- CSR build (per relation, shared by both layers) ----
    zero_int_kernel<<<(nzero + 255) / 256, 256, 0, stream>>>(ibase, nzero);
    for (int r = 0; r < 3; ++r)
        hist_kernel<<<(EC[r] + 255) / 256, 256, 0, stream>>>(dst[r], EC[r], deg[r]);
    for (int r = 0; r < 3; ++r)
        scan_kernel<<<1, 1024, 0, stream>>>(deg[r], rs[r], ndst[r]);
    for (int r = 0; r < 3; ++r)
        scatter_kernel<<<(EC[r] + 255) / 256, 256, 0, stream>>>(src[r], dst[r], EC[r],
                                                                rs[r], cur[r], esrc[r]);

    auto gblocks = [](int n) { return (n + 31) / 32; };
    auto ablocks = [](int n) { return (n + 3) / 4; };

    // ---- layer 1 ----
    gemm_kernel<128><<<gblocks(ND), 256, 0, stream>>>(x_drug, W1[0], tbuf, ND);
    agg_kernel<128, false><<<ablocks(ND), 256, 0, stream>>>(tbuf, esrc[0], rs[0], b1[0], h_d, ND);
    gemm_kernel<128><<<gblocks(ND), 256, 0, stream>>>(x_drug, W1[1], tbuf, ND);
    agg_kernel<128, false><<<ablocks(NP), 256, 0, stream>>>(tbuf, esrc[1], rs[1], b1[1], h_p, NP);
    gemm_kernel<128><<<gblocks(NP), 256, 0, stream>>>(x_prot, W1[2], tbuf, NP);
    agg_kernel<128, true><<<ablocks(NP), 256, 0, stream>>>(tbuf, esrc[2], rs[2], b1[2], h_p, NP);

    // ---- layer 2 ----
    gemm_kernel<64><<<gblocks(ND), 256, 0, stream>>>(h_d, W2[0], tbuf, ND);
    agg_kernel<64, false><<<ablocks(ND), 256, 0, stream>>>(tbuf, esrc[0], rs[0], b2[0], out, ND);
    gemm_kernel<64><<<gblocks(ND), 256, 0, stream>>>(h_d, W2[1], tbuf, ND);
    agg_kernel<64, false><<<ablocks(NP), 256, 0, stream>>>(tbuf, esrc[1], rs[1], b2[1],
                                                           out + (size_t)ND * 64, NP);
    gemm_kernel<64><<<gblocks(NP), 256, 0, stream>>>(h_p, W2[2], tbuf, NP);
    agg_kernel<64, true><<<ablocks(NP), 256, 0, stream>>>(tbuf, esrc[2], rs[2], b2[2],
                                                          out + (size_t)ND * 64, NP);
}

// Round 2
// 684.644 us; speedup vs baseline: 1.4787x; 1.4787x over previous
//
#include <hip/hip_runtime.h>

// ---------------- CSR build ----------------

__global__ void zero_int_kernel(int* __restrict__ p, int n) {
    int i = blockIdx.x * blockDim.x + threadIdx.x;
    if (i < n) p[i] = 0;
}

__global__ void hist_kernel(const int* __restrict__ dst, int n, int* __restrict__ deg) {
    int i = blockIdx.x * blockDim.x + threadIdx.x;
    if (i < n) atomicAdd(&deg[dst[i]], 1);
}

// ---- parallel exclusive scan: partial sums -> scan partials -> final ----
constexpr int SCAN_TPB = 256;
constexpr int SCAN_VPT = 4;
constexpr int SCAN_EPB = SCAN_TPB * SCAN_VPT;  // 1024

__global__ __launch_bounds__(SCAN_TPB) void scan_partial_kernel(const int* __restrict__ deg,
                                                                int n, int* __restrict__ partials) {
    __shared__ int red[SCAN_TPB];
    int t = threadIdx.x;
    int base = blockIdx.x * SCAN_EPB + t * SCAN_VPT;
    int s = 0;
    #pragma unroll
    for (int j = 0; j < SCAN_VPT; ++j) {
        int i = base + j;
        if (i < n) s += deg[i];
    }
    red[t] = s;
    __syncthreads();
    for (int off = SCAN_TPB / 2; off > 0; off >>= 1) {
        if (t < off) red[t] += red[t + off];
        __syncthreads();
    }
    if (t == 0) partials[blockIdx.x] = red[0];
}

// one wave; exclusive-scans partials in place, writes grand total to *total_out
__global__ __launch_bounds__(64) void scan_partials_kernel(int* __restrict__ partials, int nb,
                                                           int* __restrict__ total_out) {
    int lane = threadIdx.x;
    int run = 0;
    for (int base = 0; base < nb; base += 64) {
        int i = base + lane;
        int orig = (i < nb) ? partials[i] : 0;
        int v = orig;
        #pragma unroll
        for (int off = 1; off < 64; off <<= 1) {
            int u = __shfl_up(v, off);
            if (lane >= off) v += u;
        }
        if (i < nb) partials[i] = run + (v - orig);
        run += __shfl(v, 63);
    }
    if (lane == 0) *total_out = run;
}

__global__ __launch_bounds__(SCAN_TPB) void scan_final_kernel(const int* __restrict__ deg, int n,
                                                              const int* __restrict__ partials,
                                                              int* __restrict__ rs) {
    __shared__ int tsum[SCAN_TPB];
    int t = threadIdx.x;
    int base = blockIdx.x * SCAN_EPB + t * SCAN_VPT;
    int v[SCAN_VPT];
    int s = 0;
    #pragma unroll
    for (int j = 0; j < SCAN_VPT; ++j) {
        int i = base + j;
        v[j] = (i < n) ? deg[i] : 0;
        s += v[j];
    }
    tsum[t] = s;
    __syncthreads();
    // Hillis-Steele inclusive scan over thread sums
    for (int off = 1; off < SCAN_TPB; off <<= 1) {
        int add = (t >= off) ? tsum[t - off] : 0;
        __syncthreads();
        tsum[t] += add;
        __syncthreads();
    }
    int run = partials[blockIdx.x] + (t ? tsum[t - 1] : 0);
    #pragma unroll
    for (int j = 0; j < SCAN_VPT; ++j) {
        int i = base + j;
        if (i < n) rs[i] = run;
        run += v[j];
    }
}

__global__ void scatter_kernel(const int* __restrict__ src, const int* __restrict__ dst, int n,
                               const int* __restrict__ rs, int* __restrict__ cur,
                               int* __restrict__ esrc) {
    int i = blockIdx.x * blockDim.x + threadIdx.x;
    if (i < n) {
        int d = dst[i];
        int p = atomicAdd(&cur[d], 1);
        esrc[rs[d] + p] = src[i];
    }
}

// ---------------- GEMM: Y[N x M] = X[N x 128] @ W[128 x M], fp32 ----------------

template<int M>
__global__ __launch_bounds__(256) void gemm_kernel(const float* __restrict__ X,
                                                   const float* __restrict__ W,
                                                   float* __restrict__ Y, int N) {
    constexpr int CG = M / 4;       // column groups of 4
    constexpr int RG = 256 / CG;    // row groups
    constexpr int RPT = 32 / RG;    // rows per thread (tile = 32 rows)
    __shared__ float xs[128 * 33];  // transposed tile xs[k*33 + r], +1 pad vs 32
    const int row0 = blockIdx.x * 32;
    const int t = threadIdx.x;
    #pragma unroll
    for (int i = 0; i < 16; ++i) {
        int f = t + i * 256;
        int r = f >> 7, k = f & 127;
        int grow = row0 + r;
        xs[k * 33 + r] = (grow < N) ? X[(size_t)grow * 128 + k] : 0.f;
    }
    __syncthreads();
    const int c0 = (t % CG) * 4;
    const int r0 = (t / CG) * RPT;
    float acc[RPT][4];
    #pragma unroll
    for (int j = 0; j < RPT; ++j)
        acc[j][0] = acc[j][1] = acc[j][2] = acc[j][3] = 0.f;
    #pragma unroll 4
    for (int k = 0; k < 128; ++k) {
        const float4 wv = *(const float4*)&W[k * M + c0];
        #pragma unroll
        for (int j = 0; j < RPT; ++j) {
            float xv = xs[k * 33 + r0 + j];
            acc[j][0] += xv * wv.x;
            acc[j][1] += xv * wv.y;
            acc[j][2] += xv * wv.z;
            acc[j][3] += xv * wv.w;
        }
    }
    #pragma unroll
    for (int j = 0; j < RPT; ++j) {
        int rr = row0 + r0 + j;
        if (rr < N) *(float4*)&Y[(size_t)rr * M + c0] = *(const float4*)acc[j];
    }
}

// ---------------- Aggregation: one wave per dst node ----------------
// out[dst] = (sum over in-edges of h[src]) / max(deg,1) + bias   (+= if ACCUM)

template<bool ACCUM>
__global__ __launch_bounds__(256) void agg128_kernel(const float* __restrict__ h,
                                                     const int* __restrict__ esrc,
                                                     const int* __restrict__ rs,
                                                     const float* __restrict__ bias,
                                                     float* __restrict__ out, int n) {
    int wid = (int)((blockIdx.x * 256u + threadIdx.x) >> 6);
    int lane = threadIdx.x & 63;
    if (wid >= n) return;
    int e0 = rs[wid], e1 = rs[wid + 1];
    const float2* hb = (const float2*)h;   // row = 64 float2's
    float ax = 0.f, ay = 0.f;
    int e = e0;
    for (; e + 1 < e1; e += 2) {
        float2 v0 = hb[(size_t)esrc[e] * 64 + lane];
        float2 v1 = hb[(size_t)esrc[e + 1] * 64 + lane];
        ax += v0.x + v1.x;
        ay += v0.y + v1.y;
    }
    if (e < e1) {
        float2 v0 = hb[(size_t)esrc[e] * 64 + lane];
        ax += v0.x; ay += v0.y;
    }
    float inv = 1.f / (float)max(e1 - e0, 1);
    float2 bv = ((const float2*)bias)[lane];
    float2 r;
    r.x = ax * inv + bv.x;
    r.y = ay * inv + bv.y;
    float2* op = (float2*)out + (size_t)wid * 64 + lane;
    if (ACCUM) { float2 o = *op; o.x += r.x; o.y += r.y; *op = o; }
    else *op = r;
}

template<bool ACCUM>
__global__ __launch_bounds__(256) void agg64_kernel(const float* __restrict__ h,
                                                    const int* __restrict__ esrc,
                                                    const int* __restrict__ rs,
                                                    const float* __restrict__ bias,
                                                    float* __restrict__ out, int n) {
    int wid = (int)((blockIdx.x * 256u + threadIdx.x) >> 6);
    int lane = threadIdx.x & 63;
    if (wid >= n) return;
    int e0 = rs[wid], e1 = rs[wid + 1];
    float acc = 0.f;
    int e = e0;
    for (; e + 1 < e1; e += 2) {
        float v0 = h[(size_t)esrc[e] * 64 + lane];
        float v1 = h[(size_t)esrc[e + 1] * 64 + lane];
        acc += v0 + v1;
    }
    if (e < e1) acc += h[(size_t)esrc[e] * 64 + lane];
    float inv = 1.f / (float)max(e1 - e0, 1);
    float r = acc * inv + bias[lane];
    size_t o = (size_t)wid * 64 + lane;
    if (ACCUM) out[o] += r; else out[o] = r;
}

// ---------------- launch ----------------

extern "C" void kernel_launch(void* const* d_in, const int* in_sizes, int n_in,
                              void* d_out, int out_size, void* d_ws, size_t ws_size,
                              hipStream_t stream) {
    const float* x_drug = (const float*)d_in[0];
    const float* x_prot = (const float*)d_in[1];
    const int* src[3] = { (const int*)d_in[2], (const int*)d_in[4], (const int*)d_in[6] };
    const int* dst[3] = { (const int*)d_in[3], (const int*)d_in[5], (const int*)d_in[7] };
    const float* W1[3] = { (const float*)d_in[8],  (const float*)d_in[10], (const float*)d_in[12] };
    const float* b1[3] = { (const float*)d_in[9],  (const float*)d_in[11], (const float*)d_in[13] };
    const float* W2[3] = { (const float*)d_in[14], (const float*)d_in[16], (const float*)d_in[18] };
    const float* b2[3] = { (const float*)d_in[15], (const float*)d_in[17], (const float*)d_in[19] };

    const int ND = in_sizes[0] / 128;
    const int NP = in_sizes[1] / 128;
    const int EC[3] = { in_sizes[2], in_sizes[4], in_sizes[6] };
    const int ndst[3] = { ND, NP, NP };
    float* out = (float*)d_out;

    // workspace layout
    char* w = (char*)d_ws;
    const size_t maxN = (size_t)(ND > NP ? ND : NP);
    float* tbuf = (float*)w; w += maxN * 128 * sizeof(float);       // 25.6 MB
    float* h_d  = (float*)w; w += (size_t)ND * 128 * sizeof(float); // 25.6 MB
    float* h_p  = (float*)w; w += (size_t)NP * 128 * sizeof(float); // 25.6 MB
    int* ibase = (int*)w;
    int* deg[3]; int* cur[3]; int* rs[3]; int* esrc[3]; int* parts[3];
    int* ip = ibase;
    for (int r = 0; r < 3; ++r) { deg[r] = ip; ip += ndst[r]; }
    for (int r = 0; r < 3; ++r) { cur[r] = ip; ip += ndst[r]; }
    const int nzero = (int)(ip - ibase);          // deg+cur zeroed in one launch
    for (int r = 0; r < 3; ++r) { rs[r] = ip; ip += ndst[r] + 1; }
    for (int r = 0; r < 3; ++r) { esrc[r] = ip; ip += EC[r]; }
    for (int r = 0; r < 3; ++r) { parts[r] = ip; ip += 64; }

    // ---- CSR build (per relation, shared by both layers) ----
    zero_int_kernel<<<(nzero + 255) / 256, 256, 0, stream>>>(ibase, nzero);
    for (int r = 0; r < 3; ++r)
        hist_kernel<<<(EC[r] + 255) / 256, 256, 0, stream>>>(dst[r], EC[r], deg[r]);
    for (int r = 0; r < 3; ++r) {
        int nb = (ndst[r] + SCAN_EPB - 1) / SCAN_EPB;
        scan_partial_kernel<<<nb, SCAN_TPB, 0, stream>>>(deg[r], ndst[r], parts[r]);
        scan_partials_kernel<<<1, 64, 0, stream>>>(parts[r], nb, rs[r] + ndst[r]);
        scan_final_kernel<<<nb, SCAN_TPB, 0, stream>>>(deg[r], ndst[r], parts[r], rs[r]);
    }
    for (int r = 0; r < 3; ++r)
        scatter_kernel<<<(EC[r] + 255) / 256, 256, 0, stream>>>(src[r], dst[r], EC[r],
                                                                rs[r], cur[r], esrc[r]);

    auto gblocks = [](int n) { return (n + 31) / 32; };
    auto ablocks = [](int n) { return (n + 3) / 4; };

    // ---- layer 1 ----
    gemm_kernel<128><<<gblocks(ND), 256, 0, stream>>>(x_drug, W1[0], tbuf, ND);
    agg128_kernel<false><<<ablocks(ND), 256, 0, stream>>>(tbuf, esrc[0], rs[0], b1[0], h_d, ND);
    gemm_kernel<128><<<gblocks(ND), 256, 0, stream>>>(x_drug, W1[1], tbuf, ND);
    agg128_kernel<false><<<ablocks(NP), 256, 0, stream>>>(tbuf, esrc[1], rs[1], b1[1], h_p, NP);
    gemm_kernel<128><<<gblocks(NP), 256, 0, stream>>>(x_prot, W1[2], tbuf, NP);
    agg128_kernel<true><<<ablocks(NP), 256, 0, stream>>>(tbuf, esrc[2], rs[2], b1[2], h_p, NP);

    // ---- layer 2 ----
    gemm_kernel<64><<<gblocks(ND), 256, 0, stream>>>(h_d, W2[0], tbuf, ND);
    agg64_kernel<false><<<ablocks(ND), 256, 0, stream>>>(tbuf, esrc[0], rs[0], b2[0], out, ND);
    gemm_kernel<64><<<gblocks(ND), 256, 0, stream>>>(h_d, W2[1], tbuf, ND);
    agg64_kernel<false><<<ablocks(NP), 256, 0, stream>>>(tbuf, esrc[1], rs[1], b2[1],
                                                         out + (size_t)ND * 64, NP);
    gemm_kernel<64><<<gblocks(NP), 256, 0, stream>>>(h_p, W2[2], tbuf, NP);
    agg64_kernel<true><<<ablocks(NP), 256, 0, stream>>>(tbuf, esrc[2], rs[2], b2[2],
                                                        out + (size_t)ND * 64, NP);
}

// Round 3
// 580.935 us; speedup vs baseline: 1.7427x; 1.1785x over previous
//
#include <hip/hip_runtime.h>

typedef unsigned int uint32;
typedef unsigned short ushort16;
using short8 = __attribute__((ext_vector_type(8))) short;
using f32x4  = __attribute__((ext_vector_type(4))) float;

__device__ __forceinline__ float bfl(uint32 v) { return __uint_as_float(v << 16); }
__device__ __forceinline__ float bfh(uint32 v) { return __uint_as_float(v & 0xffff0000u); }
__device__ __forceinline__ ushort16 f2bf(float f) {
    uint32 u = __float_as_uint(f);
    u += 0x7fffu + ((u >> 16) & 1u);   // RNE
    return (ushort16)(u >> 16);
}
__device__ __forceinline__ uint32 pack2(float x, float y) {
    return (uint32)f2bf(x) | ((uint32)f2bf(y) << 16);
}

// ---------------- CSR build ----------------

__global__ void zero_int_kernel(int* __restrict__ p, int n) {
    int i = blockIdx.x * blockDim.x + threadIdx.x;
    if (i < n) p[i] = 0;
}

__global__ void hist_kernel(const int* __restrict__ dst, int n, int* __restrict__ deg) {
    int i = blockIdx.x * blockDim.x + threadIdx.x;
    if (i < n) atomicAdd(&deg[dst[i]], 1);
}

constexpr int SCAN_TPB = 256;
constexpr int SCAN_VPT = 4;
constexpr int SCAN_EPB = SCAN_TPB * SCAN_VPT;  // 1024

__global__ __launch_bounds__(SCAN_TPB) void scan_partial_kernel(const int* __restrict__ deg,
                                                                int n, int* __restrict__ partials) {
    __shared__ int red[SCAN_TPB];
    int t = threadIdx.x;
    int base = blockIdx.x * SCAN_EPB + t * SCAN_VPT;
    int s = 0;
    #pragma unroll
    for (int j = 0; j < SCAN_VPT; ++j) {
        int i = base + j;
        if (i < n) s += deg[i];
    }
    red[t] = s;
    __syncthreads();
    for (int off = SCAN_TPB / 2; off > 0; off >>= 1) {
        if (t < off) red[t] += red[t + off];
        __syncthreads();
    }
    if (t == 0) partials[blockIdx.x] = red[0];
}

__global__ __launch_bounds__(64) void scan_partials_kernel(int* __restrict__ partials, int nb,
                                                           int* __restrict__ total_out) {
    int lane = threadIdx.x;
    int run = 0;
    for (int base = 0; base < nb; base += 64) {
        int i = base + lane;
        int orig = (i < nb) ? partials[i] : 0;
        int v = orig;
        #pragma unroll
        for (int off = 1; off < 64; off <<= 1) {
            int u = __shfl_up(v, off);
            if (lane >= off) v += u;
        }
        if (i < nb) partials[i] = run + (v - orig);
        run += __shfl(v, 63);
    }
    if (lane == 0) *total_out = run;
}

__global__ __launch_bounds__(SCAN_TPB) void scan_final_kernel(const int* __restrict__ deg, int n,
                                                              const int* __restrict__ partials,
                                                              int* __restrict__ rs) {
    __shared__ int tsum[SCAN_TPB];
    int t = threadIdx.x;
    int base = blockIdx.x * SCAN_EPB + t * SCAN_VPT;
    int v[SCAN_VPT];
    int s = 0;
    #pragma unroll
    for (int j = 0; j < SCAN_VPT; ++j) {
        int i = base + j;
        v[j] = (i < n) ? deg[i] : 0;
        s += v[j];
    }
    tsum[t] = s;
    __syncthreads();
    for (int off = 1; off < SCAN_TPB; off <<= 1) {
        int add = (t >= off) ? tsum[t - off] : 0;
        __syncthreads();
        tsum[t] += add;
        __syncthreads();
    }
    int run = partials[blockIdx.x] + (t ? tsum[t - 1] : 0);
    #pragma unroll
    for (int j = 0; j < SCAN_VPT; ++j) {
        int i = base + j;
        if (i < n) rs[i] = run;
        run += v[j];
    }
}

__global__ void scatter_kernel(const int* __restrict__ src, const int* __restrict__ dst, int n,
                               const int* __restrict__ rs, int* __restrict__ cur,
                               int* __restrict__ esrc) {
    int i = blockIdx.x * blockDim.x + threadIdx.x;
    if (i < n) {
        int d = dst[i];
        int p = atomicAdd(&cur[d], 1);
        esrc[rs[d] + p] = src[i];
    }
}

// ---------------- conversions ----------------

// fp32 -> bf16, 4 elems/thread
__global__ void cvt_x_kernel(const float* __restrict__ in, uint32* __restrict__ out, int n4) {
    int i = blockIdx.x * blockDim.x + threadIdx.x;
    if (i < n4) {
        float4 v = ((const float4*)in)[i];
        uint32 lo = pack2(v.x, v.y);
        uint32 hi = pack2(v.z, v.w);
        ((uint2*)out)[i] = make_uint2(lo, hi);
    }
}

// W[k][M] fp32 -> Wt[n][k] bf16 (128 k)
__global__ void cvtW_kernel(const float* __restrict__ W, ushort16* __restrict__ Wt, int M) {
    int tid = blockIdx.x * blockDim.x + threadIdx.x;
    if (tid < M * 128) {
        int n = tid >> 7, k = tid & 127;
        Wt[n * 128 + k] = f2bf(W[k * M + n]);
    }
}

// ---------------- MFMA GEMM: Y[N x M](bf16) = X[N x 128](bf16) @ W (Wt[n][k] bf16) ----------------

template<int M>  // 128 or 64
__global__ __launch_bounds__(256) void gemm_bf16_kernel(const ushort16* __restrict__ X,
                                                        const ushort16* __restrict__ Wt,
                                                        ushort16* __restrict__ Y, int N) {
    constexpr int NTW = M / 64;          // n-tiles per wave (128 -> 2, 64 -> 1)
    const int w = threadIdx.x >> 6;
    const int l = threadIdx.x & 63;
    const int lr = l & 15, lg = l >> 4;
    const int row0 = blockIdx.x * 16;
    if (row0 >= N) return;

    // A fragments: A[row = lr][k = ks*32 + lg*8 + j]
    const ushort16* xr = X + (size_t)(row0 + lr) * 128 + lg * 8;
    short8 a[4];
    #pragma unroll
    for (int ks = 0; ks < 4; ++ks) a[ks] = *(const short8*)(xr + ks * 32);

    f32x4 acc[NTW];
    #pragma unroll
    for (int t = 0; t < NTW; ++t) acc[t] = (f32x4){0.f, 0.f, 0.f, 0.f};

    #pragma unroll
    for (int t = 0; t < NTW; ++t) {
        int n = w * (NTW * 16) + t * 16 + lr;   // B[col = lr][k]
        const ushort16* wr = Wt + (size_t)n * 128 + lg * 8;
        #pragma unroll
        for (int ks = 0; ks < 4; ++ks) {
            short8 b = *(const short8*)(wr + ks * 32);
            acc[t] = __builtin_amdgcn_mfma_f32_16x16x32_bf16(a[ks], b, acc[t], 0, 0, 0);
        }
    }

    // D[row = lg*4 + j][col = tile base + lr]
    #pragma unroll
    for (int t = 0; t < NTW; ++t) {
        int col = w * (NTW * 16) + t * 16 + lr;
        #pragma unroll
        for (int j = 0; j < 4; ++j) {
            int r = row0 + lg * 4 + j;
            Y[(size_t)r * M + col] = f2bf(acc[t][j]);
        }
    }
}

// ---------------- Aggregation (bf16 table) ----------------
// out[dst] = (sum h[src]) / max(deg,1) + bias   (+= if ACCUM)

// D=128: bf16 out (packed pairs)
template<bool ACCUM>
__global__ __launch_bounds__(256) void agg128_bf16_kernel(const ushort16* __restrict__ t,
                                                          const int* __restrict__ esrc,
                                                          const int* __restrict__ rs,
                                                          const float* __restrict__ bias,
                                                          uint32* __restrict__ out, int n) {
    int wid = (int)((blockIdx.x * 256u + threadIdx.x) >> 6);
    int lane = threadIdx.x & 63;
    if (wid >= n) return;
    int e0 = rs[wid], e1 = rs[wid + 1];
    const uint32* tb = (const uint32*)t;    // row = 64 dwords
    float ax = 0.f, ay = 0.f;
    int e = e0;
    for (; e + 1 < e1; e += 2) {
        uint32 v0 = tb[(size_t)esrc[e] * 64 + lane];
        uint32 v1 = tb[(size_t)esrc[e + 1] * 64 + lane];
        ax += bfl(v0) + bfl(v1);
        ay += bfh(v0) + bfh(v1);
    }
    if (e < e1) {
        uint32 v0 = tb[(size_t)esrc[e] * 64 + lane];
        ax += bfl(v0); ay += bfh(v0);
    }
    float inv = 1.f / (float)max(e1 - e0, 1);
    float2 bv = ((const float2*)bias)[lane];
    float rx = ax * inv + bv.x;
    float ry = ay * inv + bv.y;
    size_t o = (size_t)wid * 64 + lane;
    if (ACCUM) { uint32 old = out[o]; rx += bfl(old); ry += bfh(old); }
    out[o] = pack2(rx, ry);
}

// D=64: fp32 out (final). Two edges in flight via half-wave split.
template<bool ACCUM>
__global__ __launch_bounds__(256) void agg64_bf16_kernel(const ushort16* __restrict__ t,
                                                         const int* __restrict__ esrc,
                                                         const int* __restrict__ rs,
                                                         const float* __restrict__ bias,
                                                         float* __restrict__ out, int n) {
    int wid = (int)((blockIdx.x * 256u + threadIdx.x) >> 6);
    int lane = threadIdx.x & 63;
    if (wid >= n) return;
    int e0 = rs[wid], e1 = rs[wid + 1];
    int half = lane >> 5, c2 = lane & 31;
    const uint32* tb = (const uint32*)t;    // row = 32 dwords
    float ax = 0.f, ay = 0.f;
    for (int e = e0 + half; e < e1; e += 2) {
        uint32 v = tb[(size_t)esrc[e] * 32 + c2];
        ax += bfl(v); ay += bfh(v);
    }
    ax += __shfl_xor(ax, 32);
    ay += __shfl_xor(ay, 32);
    if (lane < 32) {
        float inv = 1.f / (float)max(e1 - e0, 1);
        float2 bv = ((const float2*)bias)[c2];
        float2 r;
        r.x = ax * inv + bv.x;
        r.y = ay * inv + bv.y;
        float2* op = (float2*)out + (size_t)wid * 32 + c2;
        if (ACCUM) { float2 o = *op; r.x += o.x; r.y += o.y; }
        *op = r;
    }
}

// ---------------- launch ----------------

extern "C" void kernel_launch(void* const* d_in, const int* in_sizes, int n_in,
                              void* d_out, int out_size, void* d_ws, size_t ws_size,
                              hipStream_t stream) {
    const float* x_drug = (const float*)d_in[0];
    const float* x_prot = (const float*)d_in[1];
    const int* src[3] = { (const int*)d_in[2], (const int*)d_in[4], (const int*)d_in[6] };
    const int* dst[3] = { (const int*)d_in[3], (const int*)d_in[5], (const int*)d_in[7] };
    const float* W1[3] = { (const float*)d_in[8],  (const float*)d_in[10], (const float*)d_in[12] };
    const float* b1[3] = { (const float*)d_in[9],  (const float*)d_in[11], (const float*)d_in[13] };
    const float* W2[3] = { (const float*)d_in[14], (const float*)d_in[16], (const float*)d_in[18] };
    const float* b2[3] = { (const float*)d_in[15], (const float*)d_in[17], (const float*)d_in[19] };

    const int ND = in_sizes[0] / 128;
    const int NP = in_sizes[1] / 128;
    const int EC[3] = { in_sizes[2], in_sizes[4], in_sizes[6] };
    const int ndst[3] = { ND, NP, NP };
    float* out = (float*)d_out;

    // workspace layout
    char* w = (char*)d_ws;
    const size_t maxN = (size_t)(ND > NP ? ND : NP);
    ushort16* xd16 = (ushort16*)w; w += (size_t)ND * 128 * 2;
    ushort16* xp16 = (ushort16*)w; w += (size_t)NP * 128 * 2;
    ushort16* hd16 = (ushort16*)w; w += (size_t)ND * 128 * 2;
    ushort16* hp16 = (ushort16*)w; w += (size_t)NP * 128 * 2;
    ushort16* tb16 = (ushort16*)w; w += maxN * 128 * 2;
    ushort16* Wt1[3]; ushort16* Wt2[3];
    for (int r = 0; r < 3; ++r) { Wt1[r] = (ushort16*)w; w += 128 * 128 * 2; }
    for (int r = 0; r < 3; ++r) { Wt2[r] = (ushort16*)w; w += 64 * 128 * 2; }
    int* ibase = (int*)w;
    int* deg[3]; int* cur[3]; int* rs[3]; int* esrc[3]; int* parts[3];
    int* ip = ibase;
    for (int r = 0; r < 3; ++r) { deg[r] = ip; ip += ndst[r]; }
    for (int r = 0; r < 3; ++r) { cur[r] = ip; ip += ndst[r]; }
    const int nzero = (int)(ip - ibase);
    for (int r = 0; r < 3; ++r) { rs[r] = ip; ip += ndst[r] + 1; }
    for (int r = 0; r < 3; ++r) { esrc[r] = ip; ip += EC[r]; }
    for (int r = 0; r < 3; ++r) { parts[r] = ip; ip += 64; }

    // ---- conversions (independent of CSR) ----
    {
        int n4d = ND * 32, n4p = NP * 32;
        cvt_x_kernel<<<(n4d + 255) / 256, 256, 0, stream>>>(x_drug, (uint32*)xd16, n4d);
        cvt_x_kernel<<<(n4p + 255) / 256, 256, 0, stream>>>(x_prot, (uint32*)xp16, n4p);
        for (int r = 0; r < 3; ++r) {
            cvtW_kernel<<<(128 * 128 + 255) / 256, 256, 0, stream>>>(W1[r], Wt1[r], 128);
            cvtW_kernel<<<(64 * 128 + 255) / 256, 256, 0, stream>>>(W2[r], Wt2[r], 64);
        }
    }

    // ---- CSR build ----
    zero_int_kernel<<<(nzero + 255) / 256, 256, 0, stream>>>(ibase, nzero);
    for (int r = 0; r < 3; ++r)
        hist_kernel<<<(EC[r] + 255) / 256, 256, 0, stream>>>(dst[r], EC[r], deg[r]);
    for (int r = 0; r < 3; ++r) {
        int nb = (ndst[r] + SCAN_EPB - 1) / SCAN_EPB;
        scan_partial_kernel<<<nb, SCAN_TPB, 0, stream>>>(deg[r], ndst[r], parts[r]);
        scan_partials_kernel<<<1, 64, 0, stream>>>(parts[r], nb, rs[r] + ndst[r]);
        scan_final_kernel<<<nb, SCAN_TPB, 0, stream>>>(deg[r], ndst[r], parts[r], rs[r]);
    }
    for (int r = 0; r < 3; ++r)
        scatter_kernel<<<(EC[r] + 255) / 256, 256, 0, stream>>>(src[r], dst[r], EC[r],
                                                                rs[r], cur[r], esrc[r]);

    auto gblocks = [](int n) { return (n + 15) / 16; };
    auto ablocks = [](int n) { return (n + 3) / 4; };

    // ---- layer 1 ----
    gemm_bf16_kernel<128><<<gblocks(ND), 256, 0, stream>>>(xd16, Wt1[0], tb16, ND);
    agg128_bf16_kernel<false><<<ablocks(ND), 256, 0, stream>>>(tb16, esrc[0], rs[0], b1[0],
                                                               (uint32*)hd16, ND);
    gemm_bf16_kernel<128><<<gblocks(ND), 256, 0, stream>>>(xd16, Wt1[1], tb16, ND);
    agg128_bf16_kernel<false><<<ablocks(NP), 256, 0, stream>>>(tb16, esrc[1], rs[1], b1[1],
                                                               (uint32*)hp16, NP);
    gemm_bf16_kernel<128><<<gblocks(NP), 256, 0, stream>>>(xp16, Wt1[2], tb16, NP);
    agg128_bf16_kernel<true><<<ablocks(NP), 256, 0, stream>>>(tb16, esrc[2], rs[2], b1[2],
                                                              (uint32*)hp16, NP);

    // ---- layer 2 ----
    gemm_bf16_kernel<64><<<gblocks(ND), 256, 0, stream>>>(hd16, Wt2[0], tb16, ND);
    agg64_bf16_kernel<false><<<ablocks(ND), 256, 0, stream>>>(tb16, esrc[0], rs[0], b2[0], out, ND);
    gemm_bf16_kernel<64><<<gblocks(ND), 256, 0, stream>>>(hd16, Wt2[1], tb16, ND);
    agg64_bf16_kernel<false><<<ablocks(NP), 256, 0, stream>>>(tb16, esrc[1], rs[1], b2[1],
                                                              out + (size_t)ND * 64, NP);
    gemm_bf16_kernel<64><<<gblocks(NP), 256, 0, stream>>>(hp16, Wt2[2], tb16, NP);
    agg64_bf16_kernel<true><<<ablocks(NP), 256, 0, stream>>>(tb16, esrc[2], rs[2], b2[2],
                                                             out + (size_t)ND * 64, NP);
}

// Round 5
// 457.093 us; speedup vs baseline: 2.2148x; 1.2709x over previous
//
#include <hip/hip_runtime.h>

typedef unsigned int uint32;
typedef unsigned short ushort16;
using short8 = __attribute__((ext_vector_type(8))) short;
using f32x4  = __attribute__((ext_vector_type(4))) float;

__device__ __forceinline__ float bfl(uint32 v) { return __uint_as_float(v << 16); }
__device__ __forceinline__ float bfh(uint32 v) { return __uint_as_float(v & 0xffff0000u); }
__device__ __forceinline__ ushort16 f2bf(float f) {
    uint32 u = __float_as_uint(f);
    u += 0x7fffu + ((u >> 16) & 1u);   // RNE
    return (ushort16)(u >> 16);
}
__device__ __forceinline__ uint32 pack2(float x, float y) {
    return (uint32)f2bf(x) | ((uint32)f2bf(y) << 16);
}

// ---------------- CSR build (fused over 3 relations) ----------------

__global__ void zero_int_kernel(int* __restrict__ p, int n) {
    int i = blockIdx.x * blockDim.x + threadIdx.x;
    if (i < n) p[i] = 0;
}

__global__ void hist3_kernel(const int* __restrict__ d0, const int* __restrict__ d1,
                             const int* __restrict__ d2, int e0, int e01, int e012,
                             int o1, int o2, int* __restrict__ deg) {
    int i = blockIdx.x * blockDim.x + threadIdx.x;
    if (i < e0)        atomicAdd(&deg[d0[i]], 1);
    else if (i < e01)  atomicAdd(&deg[o1 + d1[i - e0]], 1);
    else if (i < e012) atomicAdd(&deg[o2 + d2[i - e01]], 1);
}

constexpr int SCAN_TPB = 256;
constexpr int SCAN_VPT = 4;
constexpr int SCAN_EPB = SCAN_TPB * SCAN_VPT;  // 1024

__global__ __launch_bounds__(SCAN_TPB) void scan_partial_kernel(const int* __restrict__ deg,
                                                                int n, int* __restrict__ partials) {
    __shared__ int red[SCAN_TPB];
    int t = threadIdx.x;
    int base = blockIdx.x * SCAN_EPB + t * SCAN_VPT;
    int s = 0;
    #pragma unroll
    for (int j = 0; j < SCAN_VPT; ++j) {
        int i = base + j;
        if (i < n) s += deg[i];
    }
    red[t] = s;
    __syncthreads();
    for (int off = SCAN_TPB / 2; off > 0; off >>= 1) {
        if (t < off) red[t] += red[t + off];
        __syncthreads();
    }
    if (t == 0) partials[blockIdx.x] = red[0];
}

__global__ __launch_bounds__(64) void scan_partials_kernel(int* __restrict__ partials, int nb,
                                                           int* __restrict__ total_out) {
    int lane = threadIdx.x;
    int run = 0;
    for (int base = 0; base < nb; base += 64) {
        int i = base + lane;
        int orig = (i < nb) ? partials[i] : 0;
        int v = orig;
        #pragma unroll
        for (int off = 1; off < 64; off <<= 1) {
            int u = __shfl_up(v, off);
            if (lane >= off) v += u;
        }
        if (i < nb) partials[i] = run + (v - orig);
        run += __shfl(v, 63);
    }
    if (lane == 0) *total_out = run;
}

__global__ __launch_bounds__(SCAN_TPB) void scan_final_kernel(const int* __restrict__ deg, int n,
                                                              const int* __restrict__ partials,
                                                              int* __restrict__ rs) {
    __shared__ int tsum[SCAN_TPB];
    int t = threadIdx.x;
    int base = blockIdx.x * SCAN_EPB + t * SCAN_VPT;
    int v[SCAN_VPT];
    int s = 0;
    #pragma unroll
    for (int j = 0; j < SCAN_VPT; ++j) {
        int i = base + j;
        v[j] = (i < n) ? deg[i] : 0;
        s += v[j];
    }
    tsum[t] = s;
    __syncthreads();
    for (int off = 1; off < SCAN_TPB; off <<= 1) {
        int add = (t >= off) ? tsum[t - off] : 0;
        __syncthreads();
        tsum[t] += add;
        __syncthreads();
    }
    int run = partials[blockIdx.x] + (t ? tsum[t - 1] : 0);
    #pragma unroll
    for (int j = 0; j < SCAN_VPT; ++j) {
        int i = base + j;
        if (i < n) rs[i] = run;
        run += v[j];
    }
}

__global__ void scatter3_kernel(const int* __restrict__ s0, const int* __restrict__ d0,
                                const int* __restrict__ s1, const int* __restrict__ d1,
                                const int* __restrict__ s2, const int* __restrict__ d2,
                                int e0, int e01, int e012, int o1, int o2,
                                const int* __restrict__ rs, int* __restrict__ cur,
                                int* __restrict__ esrc) {
    int i = blockIdx.x * blockDim.x + threadIdx.x;
    int g, sv;
    if (i < e0)        { g = d0[i];            sv = s0[i]; }
    else if (i < e01)  { g = o1 + d1[i - e0];  sv = s1[i - e0]; }
    else if (i < e012) { g = o2 + d2[i - e01]; sv = s2[i - e01]; }
    else return;
    int p = atomicAdd(&cur[g], 1);
    esrc[rs[g] + p] = sv;
}

// ---------------- conversions (fused) ----------------

__global__ void cvt_x2_kernel(const float* __restrict__ a, int n4a,
                              const float* __restrict__ b, int n4b,
                              uint32* __restrict__ oa, uint32* __restrict__ ob) {
    int i = blockIdx.x * blockDim.x + threadIdx.x;
    if (i < n4a) {
        float4 v = ((const float4*)a)[i];
        ((uint2*)oa)[i] = make_uint2(pack2(v.x, v.y), pack2(v.z, v.w));
    } else if (i < n4a + n4b) {
        int j = i - n4a;
        float4 v = ((const float4*)b)[j];
        ((uint2*)ob)[j] = make_uint2(pack2(v.x, v.y), pack2(v.z, v.w));
    }
}

struct CvtWArgs { const float* W[6]; ushort16* Wt[6]; };

// W[k][M] fp32 -> Wt[n][k] bf16; first 3 have M=128, last 3 M=64
__global__ void cvtW_all_kernel(CvtWArgs a) {
    int i = blockIdx.x * blockDim.x + threadIdx.x;
    if (i < 3 * 16384) {
        int m = i / 16384, idx = i % 16384;
        int n = idx >> 7, k = idx & 127;
        a.Wt[m][n * 128 + k] = f2bf(a.W[m][k * 128 + n]);
    } else {
        i -= 3 * 16384;
        if (i >= 3 * 8192) return;
        int m = 3 + i / 8192, idx = i % 8192;
        int n = idx >> 7, k = idx & 127;
        a.Wt[m][n * 128 + k] = f2bf(a.W[m][k * 64 + n]);
    }
}

// ---------------- MFMA GEMM: Y[N x M](bf16) = X[N x 128](bf16) @ Wt[n][k] ----------------

template<int M>  // 128 or 64
__global__ __launch_bounds__(256) void gemm_bf16_kernel(const ushort16* __restrict__ X,
                                                        const ushort16* __restrict__ Wt,
                                                        ushort16* __restrict__ Y, int N) {
    constexpr int NTW = M / 64;
    const int w = threadIdx.x >> 6;
    const int l = threadIdx.x & 63;
    const int lr = l & 15, lg = l >> 4;
    const int row0 = blockIdx.x * 16;
    if (row0 >= N) return;

    const ushort16* xr = X + (size_t)(row0 + lr) * 128 + lg * 8;
    short8 a[4];
    #pragma unroll
    for (int ks = 0; ks < 4; ++ks) a[ks] = *(const short8*)(xr + ks * 32);

    f32x4 acc[NTW];
    #pragma unroll
    for (int t = 0; t < NTW; ++t) acc[t] = (f32x4){0.f, 0.f, 0.f, 0.f};

    #pragma unroll
    for (int t = 0; t < NTW; ++t) {
        int n = w * (NTW * 16) + t * 16 + lr;
        const ushort16* wr = Wt + (size_t)n * 128 + lg * 8;
        #pragma unroll
        for (int ks = 0; ks < 4; ++ks) {
            short8 b = *(const short8*)(wr + ks * 32);
            acc[t] = __builtin_amdgcn_mfma_f32_16x16x32_bf16(a[ks], b, acc[t], 0, 0, 0);
        }
    }

    #pragma unroll
    for (int t = 0; t < NTW; ++t) {
        int col = w * (NTW * 16) + t * 16 + lr;
        #pragma unroll
        for (int j = 0; j < 4; ++j) {
            int r = row0 + lg * 4 + j;
            Y[(size_t)r * M + col] = f2bf(acc[t][j]);
        }
    }
}

// ---------------- Aggregation (bf16 table, high-MLP, LDS-staged indices) ----------------
// out[dst] = (sum h[src]) / max(deg,1) + bias   (+= if ACCUM)
// Edge indices are staged per-wave into LDS (exec-mask-safe under divergence,
// unlike __shfl/ds_bpermute whose inactive-source-lane reads are undefined).

// D=128: half-wave per edge, uint2/lane, unroll 2 -> 4 gathers in flight
template<bool ACCUM>
__global__ __launch_bounds__(256) void agg128_bf16_kernel(const ushort16* __restrict__ t,
                                                          const int* __restrict__ esrc,
                                                          const int* __restrict__ rs,
                                                          const float* __restrict__ bias,
                                                          uint32* __restrict__ out, int n) {
    __shared__ int sidx[4][64];
    int w = threadIdx.x >> 6;
    int lane = threadIdx.x & 63;
    int wid = blockIdx.x * 4 + w;
    if (wid >= n) return;
    int e0 = rs[wid], e1 = rs[wid + 1];
    int h = lane >> 5, c = lane & 31;
    const uint2* tb = (const uint2*)t;    // row = 32 uint2 (256 B)
    float ax = 0.f, ay = 0.f, az = 0.f, aw = 0.f;
    for (int base = e0; base < e1; base += 64) {
        int cnt = min(64, e1 - base);
        if (lane < cnt) sidx[w][lane] = esrc[base + lane];  // wave-local slice: no barrier
        int j = h;
        for (; j + 2 < cnt; j += 4) {
            int i0 = sidx[w][j];
            int i1 = sidx[w][j + 2];
            uint2 v0 = tb[(size_t)i0 * 32 + c];
            uint2 v1 = tb[(size_t)i1 * 32 + c];
            ax += bfl(v0.x) + bfl(v1.x);  ay += bfh(v0.x) + bfh(v1.x);
            az += bfl(v0.y) + bfl(v1.y);  aw += bfh(v0.y) + bfh(v1.y);
        }
        if (j < cnt) {
            int i0 = sidx[w][j];
            uint2 v0 = tb[(size_t)i0 * 32 + c];
            ax += bfl(v0.x); ay += bfh(v0.x); az += bfl(v0.y); aw += bfh(v0.y);
        }
    }
    ax += __shfl_xor(ax, 32); ay += __shfl_xor(ay, 32);
    az += __shfl_xor(az, 32); aw += __shfl_xor(aw, 32);
    if (lane < 32) {
        float inv = 1.f / (float)max(e1 - e0, 1);
        float4 bv = ((const float4*)bias)[c];
        float rx = ax * inv + bv.x, ry = ay * inv + bv.y;
        float rz = az * inv + bv.z, rw = aw * inv + bv.w;
        uint2* op = (uint2*)out + (size_t)wid * 32 + c;
        if (ACCUM) {
            uint2 old = *op;
            rx += bfl(old.x); ry += bfh(old.x); rz += bfl(old.y); rw += bfh(old.y);
        }
        *op = make_uint2(pack2(rx, ry), pack2(rz, rw));
    }
}

// D=64: quarter-wave per edge, uint2/lane, unroll 2 -> 8 gathers in flight
template<bool ACCUM>
__global__ __launch_bounds__(256) void agg64_bf16_kernel(const ushort16* __restrict__ t,
                                                         const int* __restrict__ esrc,
                                                         const int* __restrict__ rs,
                                                         const float* __restrict__ bias,
                                                         float* __restrict__ out, int n) {
    __shared__ int sidx[4][64];
    int w = threadIdx.x >> 6;
    int lane = threadIdx.x & 63;
    int wid = blockIdx.x * 4 + w;
    if (wid >= n) return;
    int e0 = rs[wid], e1 = rs[wid + 1];
    int q = lane >> 4, c = lane & 15;
    const uint2* tb = (const uint2*)t;    // row = 16 uint2 (128 B)
    float ax = 0.f, ay = 0.f, az = 0.f, aw = 0.f;
    for (int base = e0; base < e1; base += 64) {
        int cnt = min(64, e1 - base);
        if (lane < cnt) sidx[w][lane] = esrc[base + lane];
        int j = q;
        for (; j + 4 < cnt; j += 8) {
            int i0 = sidx[w][j];
            int i1 = sidx[w][j + 4];
            uint2 v0 = tb[(size_t)i0 * 16 + c];
            uint2 v1 = tb[(size_t)i1 * 16 + c];
            ax += bfl(v0.x) + bfl(v1.x);  ay += bfh(v0.x) + bfh(v1.x);
            az += bfl(v0.y) + bfl(v1.y);  aw += bfh(v0.y) + bfh(v1.y);
        }
        if (j < cnt) {
            int i0 = sidx[w][j];
            uint2 v0 = tb[(size_t)i0 * 16 + c];
            ax += bfl(v0.x); ay += bfh(v0.x); az += bfl(v0.y); aw += bfh(v0.y);
        }
    }
    ax += __shfl_xor(ax, 16); ay += __shfl_xor(ay, 16);
    az += __shfl_xor(az, 16); aw += __shfl_xor(aw, 16);
    ax += __shfl_xor(ax, 32); ay += __shfl_xor(ay, 32);
    az += __shfl_xor(az, 32); aw += __shfl_xor(aw, 32);
    if (lane < 16) {
        float inv = 1.f / (float)max(e1 - e0, 1);
        float4 bv = ((const float4*)bias)[c];
        float4 r;
        r.x = ax * inv + bv.x; r.y = ay * inv + bv.y;
        r.z = az * inv + bv.z; r.w = aw * inv + bv.w;
        float4* op = (float4*)out + (size_t)wid * 16 + c;
        if (ACCUM) { float4 o = *op; r.x += o.x; r.y += o.y; r.z += o.z; r.w += o.w; }
        *op = r;
    }
}

// ---------------- launch ----------------

extern "C" void kernel_launch(void* const* d_in, const int* in_sizes, int n_in,
                              void* d_out, int out_size, void* d_ws, size_t ws_size,
                              hipStream_t stream) {
    const float* x_drug = (const float*)d_in[0];
    const float* x_prot = (const float*)d_in[1];
    const int* src[3] = { (const int*)d_in[2], (const int*)d_in[4], (const int*)d_in[6] };
    const int* dst[3] = { (const int*)d_in[3], (const int*)d_in[5], (const int*)d_in[7] };
    const float* W1[3] = { (const float*)d_in[8],  (const float*)d_in[10], (const float*)d_in[12] };
    const float* b1[3] = { (const float*)d_in[9],  (const float*)d_in[11], (const float*)d_in[13] };
    const float* W2[3] = { (const float*)d_in[14], (const float*)d_in[16], (const float*)d_in[18] };
    const float* b2[3] = { (const float*)d_in[15], (const float*)d_in[17], (const float*)d_in[19] };

    const int ND = in_sizes[0] / 128;
    const int NP = in_sizes[1] / 128;
    const int EC[3] = { in_sizes[2], in_sizes[4], in_sizes[6] };
    float* out = (float*)d_out;

    const int o1 = ND, o2 = ND + NP;
    const int TN = ND + 2 * NP;
    const int e0c = EC[0], e01 = EC[0] + EC[1], e012 = EC[0] + EC[1] + EC[2];

    // workspace layout
    char* w = (char*)d_ws;
    const size_t maxN = (size_t)(ND > NP ? ND : NP);
    ushort16* xd16 = (ushort16*)w; w += (size_t)ND * 128 * 2;
    ushort16* xp16 = (ushort16*)w; w += (size_t)NP * 128 * 2;
    ushort16* hd16 = (ushort16*)w; w += (size_t)ND * 128 * 2;
    ushort16* hp16 = (ushort16*)w; w += (size_t)NP * 128 * 2;
    ushort16* tb16 = (ushort16*)w; w += maxN * 128 * 2;
    ushort16* Wt[6];
    for (int r = 0; r < 3; ++r) { Wt[r] = (ushort16*)w; w += 128 * 128 * 2; }
    for (int r = 0; r < 3; ++r) { Wt[3 + r] = (ushort16*)w; w += 64 * 128 * 2; }
    int* ip = (int*)w;
    int* deg_all  = ip; ip += TN;
    int* cur_all  = ip; ip += TN;
    const int nzero = 2 * TN;
    int* rs_all   = ip; ip += TN + 1;
    int* esrc_all = ip; ip += e012;
    int* parts    = ip; ip += 256;

    const int* rsr[3]   = { rs_all, rs_all + o1, rs_all + o2 };

    // ---- conversions ----
    {
        int n4d = ND * 32, n4p = NP * 32;
        cvt_x2_kernel<<<(n4d + n4p + 255) / 256, 256, 0, stream>>>(x_drug, n4d, x_prot, n4p,
                                                                   (uint32*)xd16, (uint32*)xp16);
        CvtWArgs a;
        for (int r = 0; r < 3; ++r) { a.W[r] = W1[r]; a.W[3 + r] = W2[r]; }
        for (int r = 0; r < 6; ++r) a.Wt[r] = Wt[r];
        cvtW_all_kernel<<<(3 * 16384 + 3 * 8192 + 255) / 256, 256, 0, stream>>>(a);
    }

    // ---- CSR build (fused) ----
    zero_int_kernel<<<(nzero + 255) / 256, 256, 0, stream>>>(deg_all, nzero);
    hist3_kernel<<<(e012 + 255) / 256, 256, 0, stream>>>(dst[0], dst[1], dst[2],
                                                         e0c, e01, e012, o1, o2, deg_all);
    {
        int nb = (TN + SCAN_EPB - 1) / SCAN_EPB;
        scan_partial_kernel<<<nb, SCAN_TPB, 0, stream>>>(deg_all, TN, parts);
        scan_partials_kernel<<<1, 64, 0, stream>>>(parts, nb, rs_all + TN);
        scan_final_kernel<<<nb, SCAN_TPB, 0, stream>>>(deg_all, TN, parts, rs_all);
    }
    scatter3_kernel<<<(e012 + 255) / 256, 256, 0, stream>>>(src[0], dst[0], src[1], dst[1],
                                                            src[2], dst[2], e0c, e01, e012,
                                                            o1, o2, rs_all, cur_all, esrc_all);

    auto gblocks = [](int n) { return (n + 15) / 16; };
    auto ablocks = [](int n) { return (n + 3) / 4; };

    // ---- layer 1 ----
    gemm_bf16_kernel<128><<<gblocks(ND), 256, 0, stream>>>(xd16, Wt[0], tb16, ND);
    agg128_bf16_kernel<false><<<ablocks(ND), 256, 0, stream>>>(tb16, esrc_all, rsr[0], b1[0],
                                                               (uint32*)hd16, ND);
    gemm_bf16_kernel<128><<<gblocks(ND), 256, 0, stream>>>(xd16, Wt[1], tb16, ND);
    agg128_bf16_kernel<false><<<ablocks(NP), 256, 0, stream>>>(tb16, esrc_all, rsr[1], b1[1],
                                                               (uint32*)hp16, NP);
    gemm_bf16_kernel<128><<<gblocks(NP), 256, 0, stream>>>(xp16, Wt[2], tb16, NP);
    agg128_bf16_kernel<true><<<ablocks(NP), 256, 0, stream>>>(tb16, esrc_all, rsr[2], b1[2],
                                                              (uint32*)hp16, NP);

    // ---- layer 2 ----
    gemm_bf16_kernel<64><<<gblocks(ND), 256, 0, stream>>>(hd16, Wt[3], tb16, ND);
    agg64_bf16_kernel<false><<<ablocks(ND), 256, 0, stream>>>(tb16, esrc_all, rsr[0], b2[0],
                                                              out, ND);
    gemm_bf16_kernel<64><<<gblocks(ND), 256, 0, stream>>>(hd16, Wt[4], tb16, ND);
    agg64_bf16_kernel<false><<<ablocks(NP), 256, 0, stream>>>(tb16, esrc_all, rsr[1], b2[1],
                                                              out + (size_t)ND * 64, NP);
    gemm_bf16_kernel<64><<<gblocks(NP), 256, 0, stream>>>(hp16, Wt[5], tb16, NP);
    agg64_bf16_kernel<true><<<ablocks(NP), 256, 0, stream>>>(tb16, esrc_all, rsr[2], b2[2],
                                                             out + (size_t)ND * 64, NP);
}